// Round 4
// baseline (460.354 us; speedup 1.0000x reference)
//
#include <hip/hip_runtime.h>

// Problem constants: N=50000 nodes, K=16 neighbors, CT=CS=64, S=4, OUT=64.
#define CT 64
#define CS 64
#define K_NB 16
#define S_SZ 4
#define OUT_C 64

// Native clang vector type (nontemporal builtins reject HIP_vector_type).
typedef float vfloat4 __attribute__((ext_vector_type(4)));

// ---------------------------------------------------------------------------
// kt_rowlin: out[r][s] = in[r] @ W + b   (64 -> 4), used for both t and sl.
// 8 threads per row (8 channels each) + shfl-xor tree reduce: 1563 blocks
// (vs old k0's 196) so the row loads are latency-hidden by TLP.
// ---------------------------------------------------------------------------
__global__ __launch_bounds__(256) void kt_rowlin(
    const float* __restrict__ in, const float* __restrict__ W,
    const float* __restrict__ b, float* __restrict__ outp, int N)
{
    int gt = blockIdx.x * 256 + threadIdx.x;
    int r = gt >> 3, part = gt & 7;
    if (r >= N) return;
    const float4* rv = (const float4*)(in + (size_t)r * 64) + part * 2;
    const float4* W4 = (const float4*)W;   // 64 rows of float4 (S=4)
    float4 q0 = rv[0], q1 = rv[1];
    int c0 = part * 8;
    float4 acc = {0.f, 0.f, 0.f, 0.f};
    float xc[8] = {q0.x, q0.y, q0.z, q0.w, q1.x, q1.y, q1.z, q1.w};
    #pragma unroll
    for (int u = 0; u < 8; ++u) {
        float4 wv = W4[c0 + u];
        acc.x = fmaf(xc[u], wv.x, acc.x);
        acc.y = fmaf(xc[u], wv.y, acc.y);
        acc.z = fmaf(xc[u], wv.z, acc.z);
        acc.w = fmaf(xc[u], wv.w, acc.w);
    }
    #pragma unroll
    for (int m = 1; m < 8; m <<= 1) {   // 8-lane groups are wave-aligned
        acc.x += __shfl_xor(acc.x, m);
        acc.y += __shfl_xor(acc.y, m);
        acc.z += __shfl_xor(acc.z, m);
        acc.w += __shfl_xor(acc.w, m);
    }
    if (part == 0) {
        float4 bb = *(const float4*)b;
        acc.x += bb.x; acc.y += bb.y; acc.z += bb.z; acc.w += bb.w;
        ((float4*)outp)[r] = acc;
    }
}

// ---------------------------------------------------------------------------
// Inverse-index build: counts -> exclusive scan -> bucket fill.
// ---------------------------------------------------------------------------
__global__ __launch_bounds__(256) void kh_zero(
    int* __restrict__ counts, int* __restrict__ cursor, int N)
{
    int i = blockIdx.x * 256 + threadIdx.x;
    if (i < N) { counts[i] = 0; cursor[i] = 0; }
}

__global__ __launch_bounds__(256) void kh_hist(
    const int* __restrict__ nidx, int* __restrict__ counts, int NK)
{
    int p = blockIdx.x * 256 + threadIdx.x;
    if (p < NK) atomicAdd(&counts[nidx[p]], 1);
}

// Single-block exclusive scan over N (~50000) counts. 1024 threads, each a
// serial chunk; Hillis-Steele over the 1024 partials in LDS.
__global__ __launch_bounds__(1024) void kh_scan(
    const int* __restrict__ counts, int* __restrict__ offsets, int N)
{
    __shared__ int ls[1024];
    const int t = threadIdx.x;
    const int chunk = (N + 1023) >> 10;
    const int lo = t * chunk;
    const int hi = (lo + chunk < N) ? lo + chunk : N;
    int s = 0;
    for (int i = lo; i < hi; ++i) s += counts[i];
    ls[t] = s;
    __syncthreads();
    for (int off = 1; off < 1024; off <<= 1) {
        int v = (t >= off) ? ls[t - off] : 0;
        __syncthreads();
        ls[t] += v;
        __syncthreads();
    }
    int excl = ls[t] - s;   // exclusive prefix of this thread's chunk
    for (int i = lo; i < hi; ++i) { offsets[i] = excl; excl += counts[i]; }
}

__global__ __launch_bounds__(256) void kh_fill(
    const int* __restrict__ nidx, const int* __restrict__ offsets,
    int* __restrict__ cursor, int* __restrict__ plist, int NK)
{
    int p = blockIdx.x * 256 + threadIdx.x;
    if (p >= NK) return;
    int j = nidx[p];
    int pos = atomicAdd(&cursor[j], 1);
    plist[offsets[j] + pos] = p;   // order within bucket irrelevant
}

// ---------------------------------------------------------------------------
// k_main: scatter-form fused kernel. Grid-stride over source nodes j.
//   - W_lin column (64 floats) register-resident per thread, loaded ONCE
//     per block (grid-stride => ~24 j's reuse it).
//   - Z_j computed into LDS from src[j] (src read exactly once from HBM).
//   - For each p=(n,k) referencing j (from inverse index): softmax of
//     sl[j]+t[n], weighted Z mix, 256B contiguous nt-store of out[p].
// Z never touches HBM: kills the 406 MB random-gather fetch of the old k2.
// ---------------------------------------------------------------------------
__global__ __launch_bounds__(256) void k_main(
    const int* __restrict__ counts, const int* __restrict__ offsets,
    const int* __restrict__ plist, const float* __restrict__ src,
    const float* __restrict__ W_lin, const float* __restrict__ b_lin,
    const float* __restrict__ t_in, const float* __restrict__ sl_in,
    float* __restrict__ out, int N)
{
    const int col = threadIdx.x;          // col = s*64 + o
    const int s = col >> 6, o = col & 63;
    float w[64];
    #pragma unroll
    for (int c = 0; c < 64; ++c)
        w[c] = W_lin[s * 4096 + (c << 6) + o];   // coalesced in o
    const float bl = b_lin[col];
    const int g = col >> 4;               // 16 groups of 16 threads
    const int lane16 = col & 15;          // o-quad within group
    __shared__ float4 lsrc4[16];          // src[j], 64 floats
    __shared__ float4 zl4[64];            // Z_j, 256 floats [s*64+o]
    float* zl = (float*)zl4;

    for (int j = blockIdx.x; j < N; j += gridDim.x) {
        const int cnt = counts[j];        // block-uniform
        if (cnt == 0) continue;           // uniform branch: safe
        const int off = offsets[j];
        __syncthreads();                  // previous iter's readers done
        if (col < 16)
            lsrc4[col] = ((const float4*)(src + ((size_t)j << 6)))[col];
        __syncthreads();
        float a0 = bl, a1 = 0.f, a2 = 0.f, a3 = 0.f;
        #pragma unroll
        for (int c4 = 0; c4 < 16; ++c4) {
            float4 s4 = lsrc4[c4];        // LDS broadcast
            a0 = fmaf(s4.x, w[c4 * 4 + 0], a0);
            a1 = fmaf(s4.y, w[c4 * 4 + 1], a1);
            a2 = fmaf(s4.z, w[c4 * 4 + 2], a2);
            a3 = fmaf(s4.w, w[c4 * 4 + 3], a3);
        }
        zl[col] = (a0 + a1) + (a2 + a3);
        float4 slv = ((const float4*)sl_in)[j];   // block-uniform
        __syncthreads();
        for (int ib = g; ib < cnt; ib += 16) {    // 16 entries per sweep
            const int p = plist[off + ib];        // group-uniform
            const int n = p >> 4;                 // K = 16
            float4 tv = ((const float4*)t_in)[n]; // group-broadcast gather
            float l0 = tv.x + slv.x, l1 = tv.y + slv.y;
            float l2 = tv.z + slv.z, l3 = tv.w + slv.w;
            float m = fmaxf(fmaxf(l0, l1), fmaxf(l2, l3));
            float e0 = __expf(l0 - m), e1 = __expf(l1 - m);
            float e2 = __expf(l2 - m), e3 = __expf(l3 - m);
            float inv = 0.25f / (e0 + e1 + e2 + e3);
            float4 z0 = zl4[lane16], z1 = zl4[16 + lane16];
            float4 z2 = zl4[32 + lane16], z3 = zl4[48 + lane16];
            vfloat4 ov;
            ov.x = (e0 * z0.x + e1 * z1.x + e2 * z2.x + e3 * z3.x) * inv;
            ov.y = (e0 * z0.y + e1 * z1.y + e2 * z2.y + e3 * z3.y) * inv;
            ov.z = (e0 * z0.z + e1 * z1.z + e2 * z2.z + e3 * z3.z) * inv;
            ov.w = (e0 * z0.w + e1 * z1.w + e2 * z2.w + e3 * z3.w) * inv;
            __builtin_nontemporal_store(
                ov, (vfloat4*)out + (size_t)p * 16 + lane16);
        }
    }
}

extern "C" void kernel_launch(void* const* d_in, const int* in_sizes, int n_in,
                              void* d_out, int out_size, void* d_ws, size_t ws_size,
                              hipStream_t stream)
{
    const float* x   = (const float*)d_in[0];
    const float* src = (const float*)d_in[1];
    const int*   idx = (const int*)d_in[2];
    const float* Wt  = (const float*)d_in[3];
    const float* bt  = (const float*)d_in[4];
    const float* Ws  = (const float*)d_in[5];
    const float* bs  = (const float*)d_in[6];
    const float* Wl  = (const float*)d_in[7];
    const float* bl  = (const float*)d_in[8];
    float* out = (float*)d_out;

    const int N  = in_sizes[0] / CT;   // 50000
    const int NK = N * K_NB;

    // Workspace (floats first for 16B alignment of float4 accesses):
    //   t[N*4] | sl[N*4] | counts[N] | cursor[N] | offsets[N] | plist[N*K]
    float* t  = (float*)d_ws;
    float* sl = t + (size_t)N * 4;
    int* counts  = (int*)(sl + (size_t)N * 4);
    int* cursor  = counts + N;
    int* offsets = cursor + N;
    int* plist   = offsets + N;

    const int gbN  = (N + 255) / 256;
    const int gbNK = (NK + 255) / 256;
    const int gbRow = (N * 8 + 255) / 256;

    hipLaunchKernelGGL(kh_zero, dim3(gbN), dim3(256), 0, stream,
                       counts, cursor, N);
    hipLaunchKernelGGL(kh_hist, dim3(gbNK), dim3(256), 0, stream,
                       idx, counts, NK);
    hipLaunchKernelGGL(kh_scan, dim3(1), dim3(1024), 0, stream,
                       counts, offsets, N);
    hipLaunchKernelGGL(kh_fill, dim3(gbNK), dim3(256), 0, stream,
                       idx, offsets, cursor, plist, NK);
    hipLaunchKernelGGL(kt_rowlin, dim3(gbRow), dim3(256), 0, stream,
                       x, Wt, bt, t, N);
    hipLaunchKernelGGL(kt_rowlin, dim3(gbRow), dim3(256), 0, stream,
                       src, Ws, bs, sl, N);
    hipLaunchKernelGGL(k_main, dim3(2048), dim3(256), 0, stream,
                       counts, offsets, plist, src, Wl, bl, t, sl, out, N);
}

// Round 5
// 385.622 us; speedup vs baseline: 1.1938x; 1.1938x over previous
//
#include <hip/hip_runtime.h>

// Problem constants: N=50000 nodes, K=16 neighbors, CT=CS=64, S=4, OUT=64.
#define CT 64
#define CS 64
#define K_NB 16
#define S_SZ 4
#define OUT_C 64
#define CAP 64   // fixed bucket capacity; counts ~ Poisson(16), P(>64) ~ 1e-20

// Native clang vector type (nontemporal builtins reject HIP_vector_type).
typedef float vfloat4 __attribute__((ext_vector_type(4)));

// ---------------------------------------------------------------------------
// kt_rowlin: out[r][s] = in[r] @ W + b   (64 -> 4), used for both t and sl.
// 8 threads per row + shfl-xor tree reduce: 1563 blocks, latency-hidden.
// ---------------------------------------------------------------------------
__global__ __launch_bounds__(256) void kt_rowlin(
    const float* __restrict__ in, const float* __restrict__ W,
    const float* __restrict__ b, float* __restrict__ outp, int N)
{
    int gt = blockIdx.x * 256 + threadIdx.x;
    int r = gt >> 3, part = gt & 7;
    if (r >= N) return;
    const float4* rv = (const float4*)(in + (size_t)r * 64) + part * 2;
    const float4* W4 = (const float4*)W;   // 64 rows of float4 (S=4)
    float4 q0 = rv[0], q1 = rv[1];
    int c0 = part * 8;
    float4 acc = {0.f, 0.f, 0.f, 0.f};
    float xc[8] = {q0.x, q0.y, q0.z, q0.w, q1.x, q1.y, q1.z, q1.w};
    #pragma unroll
    for (int u = 0; u < 8; ++u) {
        float4 wv = W4[c0 + u];
        acc.x = fmaf(xc[u], wv.x, acc.x);
        acc.y = fmaf(xc[u], wv.y, acc.y);
        acc.z = fmaf(xc[u], wv.z, acc.z);
        acc.w = fmaf(xc[u], wv.w, acc.w);
    }
    #pragma unroll
    for (int m = 1; m < 8; m <<= 1) {   // 8-lane groups are wave-aligned
        acc.x += __shfl_xor(acc.x, m);
        acc.y += __shfl_xor(acc.y, m);
        acc.z += __shfl_xor(acc.z, m);
        acc.w += __shfl_xor(acc.w, m);
    }
    if (part == 0) {
        float4 bb = *(const float4*)b;
        acc.x += bb.x; acc.y += bb.y; acc.z += bb.z; acc.w += bb.w;
        ((float4*)outp)[r] = acc;
    }
}

// ---------------------------------------------------------------------------
// Fixed-capacity inverse index: NO histogram pass, NO scan (the round-4
// kh_scan was a single-block serial bottleneck). cursor doubles as count.
// ---------------------------------------------------------------------------
__global__ __launch_bounds__(256) void kh_zero(int* __restrict__ cursor, int N)
{
    int i = blockIdx.x * 256 + threadIdx.x;
    if (i < N) cursor[i] = 0;
}

__global__ __launch_bounds__(256) void kh_fill_fixed(
    const int* __restrict__ nidx, int* __restrict__ cursor,
    int* __restrict__ plist, int NK)
{
    int p = blockIdx.x * 256 + threadIdx.x;
    if (p >= NK) return;
    int j = nidx[p];
    int pos = atomicAdd(&cursor[j], 1);
    if (pos < CAP) plist[(size_t)j * CAP + pos] = p;
}

// ---------------------------------------------------------------------------
// k_main: scatter-form fused kernel, software-pipelined, ONE barrier per j.
// Per block: W_lin column register-resident (loaded once, reused over ~24 j).
// Per j (buffer b = parity):
//   a. compute Z[b] into LDS from lsrc[b]        (256 threads, 64 FMA each)
//   b. stage lsrc[b^1] <- src[j_next]            (16 threads, other buffer)
//   c. __syncthreads()                            (Z[b] + lsrc[b^1] visible)
//   d. sweep: for each p in bucket j: softmax(sl[j]+t[n]) mix of Z[b],
//      256B-contiguous nt-store of out[p] (write stream bypasses cache).
// Safety of 1 barrier: (d) reads only zl[b]; a racing wave's next-iter
// writes touch zl[b^1] / lsrc[b], whose last readers all finished before
// this iter's sync (c).  Z never touches HBM.
// ---------------------------------------------------------------------------
__global__ __launch_bounds__(256) void k_main(
    const int* __restrict__ cursor, const int* __restrict__ plist,
    const float* __restrict__ src,
    const float* __restrict__ W_lin, const float* __restrict__ b_lin,
    const float* __restrict__ t_in, const float* __restrict__ sl_in,
    float* __restrict__ out, int N)
{
    const int col = threadIdx.x;          // col = s*64 + o
    const int s = col >> 6, o = col & 63;
    float w[64];
    #pragma unroll
    for (int c = 0; c < 64; ++c)
        w[c] = W_lin[s * 4096 + (c << 6) + o];   // coalesced in o
    const float bl = b_lin[col];
    const int g = col >> 4;               // 16 groups of 16 threads
    const int lane16 = col & 15;          // o-quad within group
    __shared__ float4 lsrc4[2][16];       // src[j], 64 floats, double-buffered
    __shared__ float4 zl4[2][64];         // Z_j, 256 floats [s*64+o]

    const int stride = gridDim.x;
    int j = blockIdx.x;
    int b = 0;
    // Prologue: stage first src row.
    if (j < N) {
        if (col < 16)
            lsrc4[0][col] = ((const float4*)(src + ((size_t)j << 6)))[col];
        __syncthreads();
    }
    for (; j < N; j += stride, b ^= 1) {
        const int jn = j + stride;
        // a. compute Z[b] from lsrc[b]
        {
            float a0 = bl, a1 = 0.f, a2 = 0.f, a3 = 0.f;
            #pragma unroll
            for (int c4 = 0; c4 < 16; ++c4) {
                float4 s4 = lsrc4[b][c4];     // LDS broadcast
                a0 = fmaf(s4.x, w[c4 * 4 + 0], a0);
                a1 = fmaf(s4.y, w[c4 * 4 + 1], a1);
                a2 = fmaf(s4.z, w[c4 * 4 + 2], a2);
                a3 = fmaf(s4.w, w[c4 * 4 + 3], a3);
            }
            ((float*)zl4[b])[col] = (a0 + a1) + (a2 + a3);
        }
        // b. stage next src row into the other buffer
        if (jn < N && col < 16)
            lsrc4[b ^ 1][col] = ((const float4*)(src + ((size_t)jn << 6)))[col];
        // block-uniform scalars for this j
        const int cntr = cursor[j];
        const int cnt = cntr < CAP ? cntr : CAP;
        const float4 slv = ((const float4*)sl_in)[j];
        // c. one barrier
        __syncthreads();
        // d. sweep the bucket
        const int off = j * CAP;
        for (int ib = g; ib < cnt; ib += 16) {
            const int p = plist[off + ib];        // group-uniform
            const int n = p >> 4;                 // K = 16
            float4 tv = ((const float4*)t_in)[n]; // group-broadcast gather
            float l0 = tv.x + slv.x, l1 = tv.y + slv.y;
            float l2 = tv.z + slv.z, l3 = tv.w + slv.w;
            float m = fmaxf(fmaxf(l0, l1), fmaxf(l2, l3));
            float e0 = __expf(l0 - m), e1 = __expf(l1 - m);
            float e2 = __expf(l2 - m), e3 = __expf(l3 - m);
            float inv = 0.25f / (e0 + e1 + e2 + e3);
            float4 z0 = zl4[b][lane16],      z1 = zl4[b][16 + lane16];
            float4 z2 = zl4[b][32 + lane16], z3 = zl4[b][48 + lane16];
            vfloat4 ov;
            ov.x = (e0 * z0.x + e1 * z1.x + e2 * z2.x + e3 * z3.x) * inv;
            ov.y = (e0 * z0.y + e1 * z1.y + e2 * z2.y + e3 * z3.y) * inv;
            ov.z = (e0 * z0.z + e1 * z1.z + e2 * z2.z + e3 * z3.z) * inv;
            ov.w = (e0 * z0.w + e1 * z1.w + e2 * z2.w + e3 * z3.w) * inv;
            __builtin_nontemporal_store(
                ov, (vfloat4*)out + (size_t)p * 16 + lane16);
        }
    }
}

extern "C" void kernel_launch(void* const* d_in, const int* in_sizes, int n_in,
                              void* d_out, int out_size, void* d_ws, size_t ws_size,
                              hipStream_t stream)
{
    const float* x   = (const float*)d_in[0];
    const float* src = (const float*)d_in[1];
    const int*   idx = (const int*)d_in[2];
    const float* Wt  = (const float*)d_in[3];
    const float* bt  = (const float*)d_in[4];
    const float* Ws  = (const float*)d_in[5];
    const float* bs  = (const float*)d_in[6];
    const float* Wl  = (const float*)d_in[7];
    const float* bl  = (const float*)d_in[8];
    float* out = (float*)d_out;

    const int N  = in_sizes[0] / CT;   // 50000
    const int NK = N * K_NB;

    // Workspace (floats first, 16B-aligned float4 reads):
    //   t[N*4] | sl[N*4] | cursor[N] | plist[N*CAP]   (~15 MB)
    float* t  = (float*)d_ws;
    float* sl = t + (size_t)N * 4;
    int* cursor = (int*)(sl + (size_t)N * 4);
    int* plist  = cursor + N;

    const int gbN   = (N + 255) / 256;
    const int gbNK  = (NK + 255) / 256;
    const int gbRow = (N * 8 + 255) / 256;

    hipLaunchKernelGGL(kh_zero, dim3(gbN), dim3(256), 0, stream, cursor, N);
    hipLaunchKernelGGL(kh_fill_fixed, dim3(gbNK), dim3(256), 0, stream,
                       idx, cursor, plist, NK);
    hipLaunchKernelGGL(kt_rowlin, dim3(gbRow), dim3(256), 0, stream,
                       x, Wt, bt, t, N);
    hipLaunchKernelGGL(kt_rowlin, dim3(gbRow), dim3(256), 0, stream,
                       src, Ws, bs, sl, N);
    hipLaunchKernelGGL(k_main, dim3(2048), dim3(256), 0, stream,
                       cursor, plist, src, Wl, bl, t, sl, out, N);
}

// Round 6
// 379.468 us; speedup vs baseline: 1.2132x; 1.0162x over previous
//
#include <hip/hip_runtime.h>

// Problem constants: N=50000 nodes, K=16 neighbors, CT=CS=64, S=4, OUT=64.
#define CT 64
#define CS 64
#define K_NB 16
#define S_SZ 4
#define OUT_C 64
#define CAP 64   // fixed bucket capacity; counts ~ Poisson(16), P(>64) ~ 1e-20
#define JB 4     // source nodes per barrier phase in k_main

// Native clang vector type (nontemporal builtins reject HIP_vector_type).
typedef float vfloat4 __attribute__((ext_vector_type(4)));

// ---------------------------------------------------------------------------
// kt_both: t[r] = x[r]@Wt+bt and sl[r] = src[r]@Ws+bs in ONE pass.
// 8 threads per row (8 channels each) + shfl-xor tree reduce.
// ---------------------------------------------------------------------------
__global__ __launch_bounds__(256) void kt_both(
    const float* __restrict__ x, const float* __restrict__ src,
    const float* __restrict__ Wt, const float* __restrict__ bt,
    const float* __restrict__ Ws, const float* __restrict__ bs,
    float* __restrict__ t_out, float* __restrict__ sl_out, int N)
{
    int gt = blockIdx.x * 256 + threadIdx.x;
    int r = gt >> 3, part = gt & 7;
    if (r >= N) return;
    const float4* xv = (const float4*)(x   + (size_t)r * 64) + part * 2;
    const float4* sv = (const float4*)(src + (size_t)r * 64) + part * 2;
    const float4* Wt4 = (const float4*)Wt;   // 64 rows of float4 (S=4)
    const float4* Ws4 = (const float4*)Ws;
    float4 xq0 = xv[0], xq1 = xv[1];
    float4 sq0 = sv[0], sq1 = sv[1];
    int c0 = part * 8;
    float4 at = {0.f, 0.f, 0.f, 0.f};
    float4 as = {0.f, 0.f, 0.f, 0.f};
    float xc[8] = {xq0.x, xq0.y, xq0.z, xq0.w, xq1.x, xq1.y, xq1.z, xq1.w};
    float sc[8] = {sq0.x, sq0.y, sq0.z, sq0.w, sq1.x, sq1.y, sq1.z, sq1.w};
    #pragma unroll
    for (int u = 0; u < 8; ++u) {
        float4 wt = Wt4[c0 + u];
        float4 ws = Ws4[c0 + u];
        at.x = fmaf(xc[u], wt.x, at.x);
        at.y = fmaf(xc[u], wt.y, at.y);
        at.z = fmaf(xc[u], wt.z, at.z);
        at.w = fmaf(xc[u], wt.w, at.w);
        as.x = fmaf(sc[u], ws.x, as.x);
        as.y = fmaf(sc[u], ws.y, as.y);
        as.z = fmaf(sc[u], ws.z, as.z);
        as.w = fmaf(sc[u], ws.w, as.w);
    }
    #pragma unroll
    for (int m = 1; m < 8; m <<= 1) {   // 8-lane groups are wave-aligned
        at.x += __shfl_xor(at.x, m); at.y += __shfl_xor(at.y, m);
        at.z += __shfl_xor(at.z, m); at.w += __shfl_xor(at.w, m);
        as.x += __shfl_xor(as.x, m); as.y += __shfl_xor(as.y, m);
        as.z += __shfl_xor(as.z, m); as.w += __shfl_xor(as.w, m);
    }
    if (part == 0) {
        float4 bbt = *(const float4*)bt;
        float4 bbs = *(const float4*)bs;
        at.x += bbt.x; at.y += bbt.y; at.z += bbt.z; at.w += bbt.w;
        as.x += bbs.x; as.y += bbs.y; as.z += bbs.z; as.w += bbs.w;
        ((float4*)t_out)[r]  = at;
        ((float4*)sl_out)[r] = as;
    }
}

// ---------------------------------------------------------------------------
// Fixed-capacity inverse index (no histogram, no scan).
// ---------------------------------------------------------------------------
__global__ __launch_bounds__(256) void kh_zero(int* __restrict__ cursor, int N)
{
    int i = blockIdx.x * 256 + threadIdx.x;
    if (i < N) cursor[i] = 0;
}

__global__ __launch_bounds__(256) void kh_fill_fixed(
    const int* __restrict__ nidx, int* __restrict__ cursor,
    int* __restrict__ plist, int NK)
{
    int p = blockIdx.x * 256 + threadIdx.x;
    if (p >= NK) return;
    int j = __builtin_nontemporal_load(nidx + p);
    int pos = atomicAdd(&cursor[j], 1);
    if (pos < CAP) plist[(size_t)j * CAP + pos] = p;
}

// ---------------------------------------------------------------------------
// k_main: scatter-form fused kernel, JB=4 source nodes per barrier phase.
// Grid = 3125 blocks, pstride = 3125*4 = 12500 -> exactly 4 phases/block,
// 5 barriers total (vs 25 with 1 j per phase): barrier-drain amortized 4x,
// and each sweep has ~64 entries (16 groups x ~4 rounds) for store pipelining.
// Per phase (buffer b = parity):
//   a. compute Z[b][0..3] into LDS from lsrc[b]  (256 FMA/thread)
//   b. stage lsrc[b^1] <- next 4 src rows        (64 threads)
//   c. preload cnt[4], slv[4] (block-uniform -> SGPRs)
//   d. __syncthreads()
//   e. sweep 4 buckets from zl[b], 256B nt-stores of out rows
// Race-safety (1 barrier/phase): phase k+1's writes touch lsrc[b]/zl[b^1];
// their last readers (phase k's compute / phase k-1's sweep) all finished
// before phase k's barrier, which every wave passed before entering k+1.
// ---------------------------------------------------------------------------
__global__ __launch_bounds__(256) void k_main(
    const int* __restrict__ cursor, const int* __restrict__ plist,
    const float* __restrict__ src,
    const float* __restrict__ W_lin, const float* __restrict__ b_lin,
    const float* __restrict__ t_in, const float* __restrict__ sl_in,
    float* __restrict__ out, int N)
{
    const int col = threadIdx.x;          // col = s*64 + o
    const int s = col >> 6, o = col & 63;
    float w[64];
    #pragma unroll
    for (int c = 0; c < 64; ++c)
        w[c] = W_lin[s * 4096 + (c << 6) + o];   // coalesced in o
    const float bl = b_lin[col];
    const int g = col >> 4;               // 16 groups of 16 threads
    const int lane16 = col & 15;          // o-quad within group
    __shared__ float4 lsrc4[2][JB][16];   // 4 src rows, double-buffered
    __shared__ float4 zl4[2][JB][64];     // 4 Z tiles  [s*64+o]

    const int pstride = gridDim.x * JB;
    int jbase = blockIdx.x * JB;
    int b = 0;
    // Prologue: stage first JB src rows into buffer 0.
    if (col < 16 * JB) {
        int jj = col >> 4, q = col & 15;
        int j0 = jbase + jj;
        if (j0 < N)
            lsrc4[0][jj][q] = ((const float4*)src)[((size_t)j0 << 4) + q];
    }
    __syncthreads();

    for (; jbase < N; jbase += pstride, b ^= 1) {
        // a. compute Z for JB rows
        #pragma unroll
        for (int jj = 0; jj < JB; ++jj) {
            float a0 = bl, a1 = 0.f, a2 = 0.f, a3 = 0.f;
            #pragma unroll
            for (int c4 = 0; c4 < 16; ++c4) {
                float4 s4 = lsrc4[b][jj][c4];     // LDS broadcast
                a0 = fmaf(s4.x, w[c4 * 4 + 0], a0);
                a1 = fmaf(s4.y, w[c4 * 4 + 1], a1);
                a2 = fmaf(s4.z, w[c4 * 4 + 2], a2);
                a3 = fmaf(s4.w, w[c4 * 4 + 3], a3);
            }
            ((float*)zl4[b][jj])[col] = (a0 + a1) + (a2 + a3);
        }
        // b. stage next JB src rows into the other buffer
        {
            int nb = jbase + pstride;
            if (col < 16 * JB) {
                int jj = col >> 4, q = col & 15;
                int j0 = nb + jj;
                if (j0 < N)
                    lsrc4[b ^ 1][jj][q] =
                        ((const float4*)src)[((size_t)j0 << 4) + q];
            }
        }
        // c. block-uniform metadata (SGPR loads, issued before the barrier)
        int cnt[JB]; float4 slv[JB];
        #pragma unroll
        for (int jj = 0; jj < JB; ++jj) {
            int j = jbase + jj;
            if (j < N) {
                int c_ = cursor[j];
                cnt[jj] = c_ < CAP ? c_ : CAP;
                slv[jj] = ((const float4*)sl_in)[j];
            } else {
                cnt[jj] = 0;
                slv[jj] = make_float4(0.f, 0.f, 0.f, 0.f);
            }
        }
        // d. one barrier per phase
        __syncthreads();
        // e. sweep the JB buckets
        #pragma unroll
        for (int jj = 0; jj < JB; ++jj) {
            const int off = (jbase + jj) * CAP;
            const float4 sv = slv[jj];
            for (int ib = g; ib < cnt[jj]; ib += 16) {
                const int p = __builtin_nontemporal_load(plist + off + ib);
                const int n = p >> 4;                 // K = 16
                float4 tv = ((const float4*)t_in)[n]; // group-broadcast
                float l0 = tv.x + sv.x, l1 = tv.y + sv.y;
                float l2 = tv.z + sv.z, l3 = tv.w + sv.w;
                float m = fmaxf(fmaxf(l0, l1), fmaxf(l2, l3));
                float e0 = __expf(l0 - m), e1 = __expf(l1 - m);
                float e2 = __expf(l2 - m), e3 = __expf(l3 - m);
                float inv = 0.25f / (e0 + e1 + e2 + e3);
                float4 z0 = zl4[b][jj][lane16];
                float4 z1 = zl4[b][jj][16 + lane16];
                float4 z2 = zl4[b][jj][32 + lane16];
                float4 z3 = zl4[b][jj][48 + lane16];
                vfloat4 ov;
                ov.x = (e0 * z0.x + e1 * z1.x + e2 * z2.x + e3 * z3.x) * inv;
                ov.y = (e0 * z0.y + e1 * z1.y + e2 * z2.y + e3 * z3.y) * inv;
                ov.z = (e0 * z0.z + e1 * z1.z + e2 * z2.z + e3 * z3.z) * inv;
                ov.w = (e0 * z0.w + e1 * z1.w + e2 * z2.w + e3 * z3.w) * inv;
                __builtin_nontemporal_store(
                    ov, (vfloat4*)out + (size_t)p * 16 + lane16);
            }
        }
    }
}

extern "C" void kernel_launch(void* const* d_in, const int* in_sizes, int n_in,
                              void* d_out, int out_size, void* d_ws, size_t ws_size,
                              hipStream_t stream)
{
    const float* x   = (const float*)d_in[0];
    const float* src = (const float*)d_in[1];
    const int*   idx = (const int*)d_in[2];
    const float* Wt  = (const float*)d_in[3];
    const float* bt  = (const float*)d_in[4];
    const float* Ws  = (const float*)d_in[5];
    const float* bs  = (const float*)d_in[6];
    const float* Wl  = (const float*)d_in[7];
    const float* bl  = (const float*)d_in[8];
    float* out = (float*)d_out;

    const int N  = in_sizes[0] / CT;   // 50000
    const int NK = N * K_NB;

    // Workspace: t[N*4] | sl[N*4] | cursor[N] | plist[N*CAP]  (~15 MB)
    float* t  = (float*)d_ws;
    float* sl = t + (size_t)N * 4;
    int* cursor = (int*)(sl + (size_t)N * 4);
    int* plist  = cursor + N;

    const int gbN   = (N + 255) / 256;
    const int gbNK  = (NK + 255) / 256;
    const int gbRow = (N * 8 + 255) / 256;
    const int gbMain = (N + (256 * JB) - 1) / (256 * JB) * 256 / 256;  // 3125-ish
    // exact: ceil(N / JB / <phases>) -- use ceil(N/(JB*4)) phases=4
    const int mainGrid = (N + JB * 4 - 1) / (JB * 4);   // 3125 blocks, 4 phases
    (void)gbMain;

    hipLaunchKernelGGL(kh_zero, dim3(gbN), dim3(256), 0, stream, cursor, N);
    hipLaunchKernelGGL(kh_fill_fixed, dim3(gbNK), dim3(256), 0, stream,
                       idx, cursor, plist, NK);
    hipLaunchKernelGGL(kt_both, dim3(gbRow), dim3(256), 0, stream,
                       x, src, Wt, bt, Ws, bs, t, sl, N);
    hipLaunchKernelGGL(k_main, dim3(mainGrid), dim3(256), 0, stream,
                       cursor, plist, src, Wl, bl, t, sl, out, N);
}

// Round 7
// 374.181 us; speedup vs baseline: 1.2303x; 1.0141x over previous
//
#include <hip/hip_runtime.h>

// Problem constants: N=50000 nodes, K=16 neighbors, CT=CS=64, S=4, OUT=64.
#define CT 64
#define CS 64
#define K_NB 16
#define S_SZ 4
#define OUT_C 64
#define CAP 64    // fixed bucket capacity; counts ~ Poisson(16), P(>64) ~ 1e-20
#define JB 8      // source nodes per barrier phase in k_main
#define PHASES 4  // phases per block in k_main

// Native clang vector types (nontemporal builtins reject HIP_vector_type).
typedef float vfloat4 __attribute__((ext_vector_type(4)));
typedef int   vint4   __attribute__((ext_vector_type(4)));

// ---------------------------------------------------------------------------
// kt_both: t[r] = x[r]@Wt+bt and sl[r] = src[r]@Ws+bs in ONE pass.
// Also zeroes cursor[] (grid covers N; saves the kh_zero launch — stream
// order guarantees kh_fill sees the zeros).
// ---------------------------------------------------------------------------
__global__ __launch_bounds__(256) void kt_both(
    const float* __restrict__ x, const float* __restrict__ src,
    const float* __restrict__ Wt, const float* __restrict__ bt,
    const float* __restrict__ Ws, const float* __restrict__ bs,
    float* __restrict__ t_out, float* __restrict__ sl_out,
    int* __restrict__ cursor, int N)
{
    int gt = blockIdx.x * 256 + threadIdx.x;
    if (gt < N) cursor[gt] = 0;          // fused index-zeroing
    int r = gt >> 3, part = gt & 7;
    if (r >= N) return;
    const float4* xv = (const float4*)(x   + (size_t)r * 64) + part * 2;
    const float4* sv = (const float4*)(src + (size_t)r * 64) + part * 2;
    const float4* Wt4 = (const float4*)Wt;   // 64 rows of float4 (S=4)
    const float4* Ws4 = (const float4*)Ws;
    float4 xq0 = xv[0], xq1 = xv[1];
    float4 sq0 = sv[0], sq1 = sv[1];
    int c0 = part * 8;
    float4 at = {0.f, 0.f, 0.f, 0.f};
    float4 as = {0.f, 0.f, 0.f, 0.f};
    float xc[8] = {xq0.x, xq0.y, xq0.z, xq0.w, xq1.x, xq1.y, xq1.z, xq1.w};
    float sc[8] = {sq0.x, sq0.y, sq0.z, sq0.w, sq1.x, sq1.y, sq1.z, sq1.w};
    #pragma unroll
    for (int u = 0; u < 8; ++u) {
        float4 wt = Wt4[c0 + u];
        float4 ws = Ws4[c0 + u];
        at.x = fmaf(xc[u], wt.x, at.x);
        at.y = fmaf(xc[u], wt.y, at.y);
        at.z = fmaf(xc[u], wt.z, at.z);
        at.w = fmaf(xc[u], wt.w, at.w);
        as.x = fmaf(sc[u], ws.x, as.x);
        as.y = fmaf(sc[u], ws.y, as.y);
        as.z = fmaf(sc[u], ws.z, as.z);
        as.w = fmaf(sc[u], ws.w, as.w);
    }
    #pragma unroll
    for (int m = 1; m < 8; m <<= 1) {   // 8-lane groups are wave-aligned
        at.x += __shfl_xor(at.x, m); at.y += __shfl_xor(at.y, m);
        at.z += __shfl_xor(at.z, m); at.w += __shfl_xor(at.w, m);
        as.x += __shfl_xor(as.x, m); as.y += __shfl_xor(as.y, m);
        as.z += __shfl_xor(as.z, m); as.w += __shfl_xor(as.w, m);
    }
    if (part == 0) {
        float4 bbt = *(const float4*)bt;
        float4 bbs = *(const float4*)bs;
        at.x += bbt.x; at.y += bbt.y; at.z += bbt.z; at.w += bbt.w;
        as.x += bbs.x; as.y += bbs.y; as.z += bbs.z; as.w += bbs.w;
        ((float4*)t_out)[r]  = at;
        ((float4*)sl_out)[r] = as;
    }
}

// ---------------------------------------------------------------------------
// kh_fill: fixed-capacity inverse index (no histogram, no scan).
// int4 idx loads: 4 entries per thread, 1/4 the waves of the scalar version.
// ---------------------------------------------------------------------------
__global__ __launch_bounds__(256) void kh_fill_fixed(
    const int* __restrict__ nidx, int* __restrict__ cursor,
    int* __restrict__ plist, int NK)
{
    int q = blockIdx.x * 256 + threadIdx.x;   // handles 4 consecutive p
    int p0 = q << 2;
    if (p0 >= NK) return;
    vint4 jv = __builtin_nontemporal_load((const vint4*)nidx + q);
    #pragma unroll
    for (int u = 0; u < 4; ++u) {
        int j = jv[u];
        int pos = atomicAdd(&cursor[j], 1);
        if (pos < CAP) plist[(size_t)j * CAP + pos] = p0 + u;
    }
}

// ---------------------------------------------------------------------------
// k_main: scatter-form fused kernel. JB=8 nodes per barrier phase, grid 1563
// (pstride 12504 -> <=4 phases/block; every j covered exactly once).
// Per phase (parity b):
//   a. compute Z[b][0..7] into LDS              (512 FMA/thread)
//   b. stage lsrc[b^1] <- next 8 src rows       (128 threads)
//   c. counts -> cumulative register chain m1..m8; slv -> slv_l[b] in LDS
//   d. __syncthreads()
//   e. FLAT sweep over all m8 entries of the 8 buckets: 16-thread group g
//      takes entries e = g, g+16, ... Bucket located via 7 static compares;
//      next entry's (p, t[n]) prefetched one iteration ahead so the
//      dependent plist->t chain (~2x L2 latency) is hidden.
// Race-safety (1 barrier/phase): writes of phase k+1 touch lsrc[b]/zl[b^1]/
// slv_l[b^1]; last readers of those buffers all sit BEFORE the barrier every
// wave passed (phase k's compute / phase k-1's sweep, which precedes phase
// k's barrier in program order). slv_l is written in (c) of the USING phase,
// so its overwrite comes 2 phases later - after the sweep provably retired.
// ---------------------------------------------------------------------------
__global__ __launch_bounds__(256) void k_main(
    const int* __restrict__ cursor, const int* __restrict__ plist,
    const float* __restrict__ src,
    const float* __restrict__ W_lin, const float* __restrict__ b_lin,
    const float* __restrict__ t_in, const float* __restrict__ sl_in,
    float* __restrict__ out, int N)
{
    const int col = threadIdx.x;          // col = s*64 + o
    const int s = col >> 6, o = col & 63;
    float w[64];
    #pragma unroll
    for (int c = 0; c < 64; ++c)
        w[c] = W_lin[s * 4096 + (c << 6) + o];   // coalesced in o
    const float bl = b_lin[col];
    const int g = col >> 4;               // 16 groups of 16 threads
    const int lane16 = col & 15;          // o-quad within group
    __shared__ float4 lsrc4[2][JB][16];   // 8 src rows, double-buffered
    __shared__ float4 zl4[2][JB][64];     // 8 Z tiles [s*64+o]
    __shared__ float4 slv_l[2][JB];       // 8 sl vectors (dyn-indexed in sweep)

    const int pstride = gridDim.x * JB;
    int jbase = blockIdx.x * JB;
    int b = 0;
    // Prologue: stage first JB src rows into buffer 0.
    if (col < 16 * JB) {
        int jj = col >> 4, q = col & 15;
        int j0 = jbase + jj;
        if (j0 < N)
            lsrc4[0][jj][q] = ((const float4*)src)[((size_t)j0 << 4) + q];
    }
    __syncthreads();

    for (; jbase < N; jbase += pstride, b ^= 1) {
        // a. compute Z for JB rows
        #pragma unroll
        for (int jj = 0; jj < JB; ++jj) {
            float a0 = bl, a1 = 0.f, a2 = 0.f, a3 = 0.f;
            #pragma unroll
            for (int c4 = 0; c4 < 16; ++c4) {
                float4 s4 = lsrc4[b][jj][c4];     // LDS broadcast
                a0 = fmaf(s4.x, w[c4 * 4 + 0], a0);
                a1 = fmaf(s4.y, w[c4 * 4 + 1], a1);
                a2 = fmaf(s4.z, w[c4 * 4 + 2], a2);
                a3 = fmaf(s4.w, w[c4 * 4 + 3], a3);
            }
            ((float*)zl4[b][jj])[col] = (a0 + a1) + (a2 + a3);
        }
        // b. stage next JB src rows into the other buffer
        {
            int nb = jbase + pstride;
            if (col < 16 * JB) {
                int jj = col >> 4, q = col & 15;
                int j0 = nb + jj;
                if (j0 < N)
                    lsrc4[b ^ 1][jj][q] =
                        ((const float4*)src)[((size_t)j0 << 4) + q];
            }
        }
        // c. metadata: slv -> LDS (current parity), counts -> cum chain
        if (col < JB) {
            int j0 = jbase + col;
            slv_l[b][col] = (j0 < N) ? ((const float4*)sl_in)[j0]
                                     : make_float4(0.f, 0.f, 0.f, 0.f);
        }
        int cA[JB];
        #pragma unroll
        for (int jj = 0; jj < JB; ++jj) {
            int j0 = jbase + jj;
            int c_ = (j0 < N) ? cursor[j0] : 0;
            cA[jj] = c_ < CAP ? c_ : CAP;
        }
        const int m1 = cA[0],      m2 = m1 + cA[1], m3 = m2 + cA[2];
        const int m4 = m3 + cA[3], m5 = m4 + cA[4], m6 = m5 + cA[5];
        const int m7 = m6 + cA[6], m8 = m7 + cA[7];
        // d. one barrier per phase
        __syncthreads();
        // e. flat software-pipelined sweep over all entries of the 8 buckets
        const int total = m8;
        const size_t pbase = (size_t)jbase * CAP;
        int e = g;
        int p_pre = 0;
        float4 tv_pre = make_float4(0.f, 0.f, 0.f, 0.f);
        if (e < total) {
            int jj = (e >= m1) + (e >= m2) + (e >= m3) + (e >= m4)
                   + (e >= m5) + (e >= m6) + (e >= m7);
            int lo = 0;
            lo = e >= m1 ? m1 : lo; lo = e >= m2 ? m2 : lo;
            lo = e >= m3 ? m3 : lo; lo = e >= m4 ? m4 : lo;
            lo = e >= m5 ? m5 : lo; lo = e >= m6 ? m6 : lo;
            lo = e >= m7 ? m7 : lo;
            p_pre = __builtin_nontemporal_load(
                        plist + pbase + jj * CAP + (e - lo));
            tv_pre = ((const float4*)t_in)[p_pre >> 4];
        }
        while (e < total) {
            const int p_cur = p_pre;
            const float4 tv = tv_pre;
            const int jj = (e >= m1) + (e >= m2) + (e >= m3) + (e >= m4)
                         + (e >= m5) + (e >= m6) + (e >= m7);
            const int en = e + 16;
            if (en < total) {             // prefetch next entry's p and t[n]
                int jn = (en >= m1) + (en >= m2) + (en >= m3) + (en >= m4)
                       + (en >= m5) + (en >= m6) + (en >= m7);
                int lo = 0;
                lo = en >= m1 ? m1 : lo; lo = en >= m2 ? m2 : lo;
                lo = en >= m3 ? m3 : lo; lo = en >= m4 ? m4 : lo;
                lo = en >= m5 ? m5 : lo; lo = en >= m6 ? m6 : lo;
                lo = en >= m7 ? m7 : lo;
                p_pre = __builtin_nontemporal_load(
                            plist + pbase + jn * CAP + (en - lo));
                tv_pre = ((const float4*)t_in)[p_pre >> 4];
            }
            const float4 sv = slv_l[b][jj];     // LDS broadcast
            float l0 = tv.x + sv.x, l1 = tv.y + sv.y;
            float l2 = tv.z + sv.z, l3 = tv.w + sv.w;
            float m = fmaxf(fmaxf(l0, l1), fmaxf(l2, l3));
            float e0 = __expf(l0 - m), e1 = __expf(l1 - m);
            float e2 = __expf(l2 - m), e3 = __expf(l3 - m);
            float inv = 0.25f / (e0 + e1 + e2 + e3);
            float4 z0 = zl4[b][jj][lane16];
            float4 z1 = zl4[b][jj][16 + lane16];
            float4 z2 = zl4[b][jj][32 + lane16];
            float4 z3 = zl4[b][jj][48 + lane16];
            vfloat4 ov;
            ov.x = (e0 * z0.x + e1 * z1.x + e2 * z2.x + e3 * z3.x) * inv;
            ov.y = (e0 * z0.y + e1 * z1.y + e2 * z2.y + e3 * z3.y) * inv;
            ov.z = (e0 * z0.z + e1 * z1.z + e2 * z2.z + e3 * z3.z) * inv;
            ov.w = (e0 * z0.w + e1 * z1.w + e2 * z2.w + e3 * z3.w) * inv;
            __builtin_nontemporal_store(
                ov, (vfloat4*)out + (size_t)p_cur * 16 + lane16);
            e = en;
        }
    }
}

extern "C" void kernel_launch(void* const* d_in, const int* in_sizes, int n_in,
                              void* d_out, int out_size, void* d_ws, size_t ws_size,
                              hipStream_t stream)
{
    const float* x   = (const float*)d_in[0];
    const float* src = (const float*)d_in[1];
    const int*   idx = (const int*)d_in[2];
    const float* Wt  = (const float*)d_in[3];
    const float* bt  = (const float*)d_in[4];
    const float* Ws  = (const float*)d_in[5];
    const float* bs  = (const float*)d_in[6];
    const float* Wl  = (const float*)d_in[7];
    const float* bl  = (const float*)d_in[8];
    float* out = (float*)d_out;

    const int N  = in_sizes[0] / CT;   // 50000
    const int NK = N * K_NB;

    // Workspace: t[N*4] | sl[N*4] | cursor[N] | plist[N*CAP]  (~15 MB)
    float* t  = (float*)d_ws;
    float* sl = t + (size_t)N * 4;
    int* cursor = (int*)(sl + (size_t)N * 4);
    int* plist  = cursor + N;

    const int gbRow  = (N * 8 + 255) / 256;              // 1563
    const int gbFill = (NK / 4 + 255) / 256;             // 782
    const int mainGrid = (N + JB * PHASES - 1) / (JB * PHASES);  // 1563

    hipLaunchKernelGGL(kt_both, dim3(gbRow), dim3(256), 0, stream,
                       x, src, Wt, bt, Ws, bs, t, sl, cursor, N);
    hipLaunchKernelGGL(kh_fill_fixed, dim3(gbFill), dim3(256), 0, stream,
                       idx, cursor, plist, NK);
    hipLaunchKernelGGL(k_main, dim3(mainGrid), dim3(256), 0, stream,
                       cursor, plist, src, Wl, bl, t, sl, out, N);
}